// Round 7
// baseline (286.820 us; speedup 1.0000x reference)
//
#include <hip/hip_runtime.h>

#define BATCH 16384
#define LSEQ  50
#define DIN   20
#define CHN   16
#define HID   6

typedef float vf2 __attribute__((ext_vector_type(2)));

__device__ __forceinline__ float frcp(float x){ return __builtin_amdgcn_rcpf(x); }
__device__ __forceinline__ float fexp2(float x){
#if __has_builtin(__builtin_amdgcn_exp2f)
  return __builtin_amdgcn_exp2f(x);
#else
  return exp2f(x);
#endif
}
// exp(x) = 2^(x*log2e); constants pre-folded to keep one v_mul + one v_exp per call
#define LOG2E 1.4426950408889634f
__device__ __forceinline__ float fsig(float x){ return frcp(1.0f + fexp2(-LOG2E * x)); }
__device__ __forceinline__ float ftanh(float x){ float t = fexp2((2.0f*LOG2E)*x); return (t - 1.0f) * frcp(t + 1.0f); }
__device__ __forceinline__ float lrelu(float v){ return v > 0.0f ? v : 0.1f*v; }
__device__ __forceinline__ vf2 fma2(vf2 a, vf2 b, vf2 c){
#if __has_builtin(__builtin_elementwise_fma)
  return __builtin_elementwise_fma(a, b, c);
#else
  vf2 r; r.x = fmaf(a.x, b.x, c.x); r.y = fmaf(a.y, b.y, c.y); return r;
#endif
}
// exp(s/6) = 2^(s * log2e/6)
#define KEXP 0.24044917348149793f

// uniform broadcast of lane l's value (SALU path, ignores exec mask)
__device__ __forceinline__ float readlane_f(float v, int l){
  return __int_as_float(__builtin_amdgcn_readlane(__float_as_int(v), l));
}

// Intra-wave LDS ordering fence (cross-lane deps within the single wave).
#define WAVE_FENCE() asm volatile("s_waitcnt lgkmcnt(0)" ::: "memory")

// Single-wave block; per-block LDS slab, SLAB = 2872 floats = 11488 B.
//  [0,840)     sXEp: padded conv rows, stride 52: P[i][2+m] = xe_flat[i*50+m].
//              sY aliases [0,300) (live after conv phase is done).
//  [840,1740)  gi rows [50][18] in TRIPLET order: [l][3h+{r,z,n}]. After GRU:
//                sATt [16][52] in [840,1672)  (transposed attn)
//                sFE  at [1672,1726)          (dead gi tail)
//                sC   [50][16] XOR-swizzled in [840,1640)
//  [1740,2040) sX4: x4 flat (l*6+h)
//  [2040,2872) sB : SHIFTED copy, B[q] = P[q+1] — makes conv's odd XP pairs
//              8B-aligned ds_read_b64 (kills ~16 v_mov repacks per conv i-iter)
constexpr int SLAB = 2872;

__global__ __launch_bounds__(64, 4) void fused_kernel(
    const float* __restrict__ x,
    const float* __restrict__ we_w, const float* __restrict__ we_b,
    const float* __restrict__ attn_w, const float* __restrict__ attn_b,
    const float* __restrict__ c1w, const float* __restrict__ c1b,
    const float* __restrict__ c2w, const float* __restrict__ c2b,
    const float* __restrict__ c3w, const float* __restrict__ c3b,
    const float* __restrict__ wih, const float* __restrict__ whh,
    const float* __restrict__ bih, const float* __restrict__ bhh,
    const float* __restrict__ fc3w, const float* __restrict__ fc3b,
    float* __restrict__ out)
{
  __shared__ __align__(16) float smem[SLAB];
  const int lane = threadIdx.x;   // 64 threads = 1 wave
  const int b    = blockIdx.x;

  float* S    = smem;
  float* sXEp = S;
  float* sY   = S;          // alias, live after conv
  float* R1   = S + 840;    // gi -> sATt/sC
  float* sFE  = S + 1672;   // R1 + 832
  float* sX4  = S + 1740;
  float* sB   = S + 2040;

  const float* xb = x + (size_t)b * (LSEQ * DIN);

  // ---- zero the shared row pads (P and the shifted copy B) ----
  if (lane < CHN) {
    sXEp[lane * 52]     = 0.0f;   // P[i][0]
    sXEp[lane * 52 + 1] = 0.0f;   // P[i][1]
    sB[lane * 52]       = 0.0f;   // B[i][0]  = P[i][1]
    sB[lane * 52 + 51]  = 0.0f;   // B[i][51] = P[i+1][0]
  } else if (lane == 16) {
    sXEp[832] = 0.0f;
    sXEp[833] = 0.0f;
  }

  // ---- Phase 1+3: lane l computes xe[l][0..15] (scatter to padded rows, twice) and gi[l][0..17] ----
  if (lane < LSEQ) {
    vf2 xv2[10];
    const float4* xr = (const float4*)(xb + lane * DIN);
    #pragma unroll
    for (int q = 0; q < 5; ++q) {
      float4 v = xr[q];
      vf2 p0; p0.x = v.x; p0.y = v.y;
      vf2 p1; p1.x = v.z; p1.y = v.w;
      xv2[2*q] = p0; xv2[2*q+1] = p1;
    }
    float xe[CHN];
    #pragma unroll
    for (int c = 0; c < CHN; ++c) {
      const vf2* wr = (const vf2*)(we_w + c * DIN);
      vf2 a2; a2.x = we_b[c]; a2.y = 0.0f;
      #pragma unroll
      for (int dp = 0; dp < 10; ++dp) a2 = fma2(xv2[dp], wr[dp], a2);
      xe[c] = a2.x + a2.y;
    }
    // scatter: kk = 16*lane + c ; i = kk/50, m = kk%50 ; addr = 52i + 2 + m
    // B copy is the same value at (addr - 1): B[q] = P[q+1] globally.
    const int kk0 = lane * CHN;
    const int i0  = kk0 / 50;
    const int m0  = kk0 - i0 * 50;
    float* basep  = sXEp + i0 * 52 + 2 + m0;
    float* basepB = sB   + i0 * 52 + 1 + m0;
    #pragma unroll
    for (int c = 0; c < CHN; ++c) {
      const int off = c + ((m0 + c >= 50) ? 2 : 0);
      basep[off]  = xe[c];
      basepB[off] = xe[c];
    }
    vf2 xe2[8];
    #pragma unroll
    for (int p = 0; p < 8; ++p) { xe2[p].x = xe[2*p]; xe2[p].y = xe[2*p+1]; }
    float gi[18];
    #pragma unroll
    for (int g = 0; g < 18; ++g) {
      const vf2* wr = (const vf2*)(wih + g * CHN);
      vf2 a2; a2.x = bih[g]; a2.y = 0.0f;
      #pragma unroll
      for (int p = 0; p < 8; ++p) a2 = fma2(xe2[p], wr[p], a2);
      gi[g] = a2.x + a2.y;
    }
    // TRIPLET store: flat[f] = gi[(f%3)*6 + f/3]  ->  lane h reads (r,z,n) at 3h
    float2* gd = (float2*)(R1 + lane * 18);
    gd[0] = make_float2(gi[0],  gi[6]);
    gd[1] = make_float2(gi[12], gi[1]);
    gd[2] = make_float2(gi[7],  gi[13]);
    gd[3] = make_float2(gi[2],  gi[8]);
    gd[4] = make_float2(gi[14], gi[3]);
    gd[5] = make_float2(gi[9],  gi[15]);
    gd[6] = make_float2(gi[4],  gi[10]);
    gd[7] = make_float2(gi[16], gi[5]);
    gd[8] = make_float2(gi[11], gi[17]);
  }
  WAVE_FENCE();      // gi + sXEp + sB ready (cross-lane within this wave)

  // ---- Phase 4: GRU — zero-shuffle 6-lane form with REGISTER h-broadcast:
  // v_readlane (SALU, ignores exec) replaces the LDS write->read round-trip
  // on the recurrence chain (~60cy -> ~15cy per step). sX4 store stays but is
  // off-chain (consumed only after the phase fence). Same fma pairing as
  // before -> bit-identical results.
  if (lane < HID) {
    const int h = lane;
    vf2 wr2[3], wz2[3], wn2[3];
    #pragma unroll
    for (int k = 0; k < 3; ++k) {
      const float2 a = *(const float2*)(whh + h        * HID + 2*k);
      const float2 c = *(const float2*)(whh + (6 + h)  * HID + 2*k);
      const float2 d = *(const float2*)(whh + (12 + h) * HID + 2*k);
      wr2[k].x = a.x; wr2[k].y = a.y;
      wz2[k].x = c.x; wz2[k].y = c.y;
      wn2[k].x = d.x; wn2[k].y = d.y;
    }
    const float br = bhh[h], bz = bhh[6 + h], bn = bhh[12 + h];

    vf2 hh2[3];
    #pragma unroll
    for (int k = 0; k < 3; ++k) hh2[k] = (vf2)0.0f;
    float hprev = 0.0f;

    // software-pipelined gi reads (l=49 prefetch lands in sX4 region: junk, unused)
    const float* gp = R1 + 3 * h;
    float gR = gp[0];
    float gZ = gp[1];
    float gN = gp[2];
    for (int l = 0; l < LSEQ; ++l) {
      const float gir = gR, giz = gZ, gin = gN;
      gp += 18;
      gR = gp[0];
      gZ = gp[1];
      gN = gp[2];
      vf2 ar; ar.x = br; ar.y = 0.0f;
      vf2 az; az.x = bz; az.y = 0.0f;
      vf2 an; an.x = bn; an.y = 0.0f;
      #pragma unroll
      for (int k = 0; k < 3; ++k) {
        ar = fma2(wr2[k], hh2[k], ar);
        az = fma2(wz2[k], hh2[k], az);
        an = fma2(wn2[k], hh2[k], an);
      }
      const float dr = ar.x + ar.y;
      const float dz = az.x + az.y;
      const float dn = an.x + an.y;
      const float r  = fsig(gir + dr);
      const float z  = fsig(giz + dz);
      const float n  = ftanh(fmaf(r, dn, gin));
      const float hn = fmaf(z, hprev - n, n);
      hprev = hn;
      sX4[l * HID + h] = hn;      // off-chain; visibility via phase fence
      const float h0 = readlane_f(hn, 0);
      const float h1 = readlane_f(hn, 1);
      const float h2 = readlane_f(hn, 2);
      const float h3 = readlane_f(hn, 3);
      const float h4 = readlane_f(hn, 4);
      const float h5 = readlane_f(hn, 5);
      hh2[0].x = h0; hh2[0].y = h1;
      hh2[1].x = h2; hh2[1].y = h3;
      hh2[2].x = h4; hh2[2].y = h5;
    }
  }
  WAVE_FENCE();      // x4 ready; gi dead (sATt may overwrite)

  // ---- Phase 2: attn rows -> TRANSPOSED sATt[16][52] (conflict-free b32 writes) ----
  // attn input is the RESHAPE view xe_flat[c*50+l] -> LDS gather is mandatory.
  {
    float* sATt = R1;
    if (lane < LSEQ) {
      float a[CHN];
      #pragma unroll
      for (int cc = 0; cc < CHN; ++cc) a[cc] = sXEp[cc * 52 + 2 + lane];  // reshape view
      vf2 a2[8];
      #pragma unroll
      for (int p = 0; p < 8; ++p) { a2[p].x = a[2*p]; a2[p].y = a[2*p+1]; }
      #pragma unroll
      for (int c = 0; c < CHN; ++c) {
        const vf2* wr = (const vf2*)(attn_w + c * CHN);
        vf2 s2; s2.x = attn_b[c]; s2.y = 0.0f;
        #pragma unroll
        for (int p = 0; p < 8; ++p) s2 = fma2(a2[p], wr[p], s2);
        sATt[c * 52 + lane] = ftanh(s2.x + s2.y);
      }
    }
  }
  WAVE_FENCE();      // sATt -> conv

  // ---- Phase 5: convs fused with attn1 reduction. Even XP pairs alias the
  // b128 quads; odd XP pairs are aligned b64 reads from the shifted copy sB.
  {
    const float* sATt = R1;
    const int o   = lane & 15;
    const int seg = lane >> 4;
    const int s   = seg * 12;
    vf2 Z1[7], Z2[7], Z3[7];
    #pragma unroll
    for (int p = 0; p < 7; ++p) {
      Z1[p] = (vf2)0.0f; Z2[p] = (vf2)0.0f; Z3[p] = (vf2)0.0f;
    }
    for (int i = 0; i < CHN; ++i) {
      const float w1s = c1w[o * CHN + i];
      vf2 W1; W1.x = w1s; W1.y = w1s;
      vf2 W2[3], W3[5];
      #pragma unroll
      for (int t = 0; t < 3; ++t) { float w = c2w[(o * CHN + i) * 3 + t]; W2[t].x = w; W2[t].y = w; }
      #pragma unroll
      for (int t = 0; t < 5; ++t) { float w = c3w[(o * CHN + i) * 5 + t]; W3[t].x = w; W3[t].y = w; }
      const float* Arow = sXEp + i * 52 + s;
      const float* Brow = sB   + i * 52 + s;
      const float4 q0 = *(const float4*)(Arow);
      const float4 q1 = *(const float4*)(Arow + 4);
      const float4 q2 = *(const float4*)(Arow + 8);
      const float4 q3 = *(const float4*)(Arow + 12);
      const float2 q4 = *(const float2*)(Arow + 16);
      vf2 XP[17];
      XP[0].x  = q0.x; XP[0].y  = q0.y;
      XP[2].x  = q0.z; XP[2].y  = q0.w;
      XP[4].x  = q1.x; XP[4].y  = q1.y;
      XP[6].x  = q1.z; XP[6].y  = q1.w;
      XP[8].x  = q2.x; XP[8].y  = q2.y;
      XP[10].x = q2.z; XP[10].y = q2.w;
      XP[12].x = q3.x; XP[12].y = q3.y;
      XP[14].x = q3.z; XP[14].y = q3.w;
      XP[16].x = q4.x; XP[16].y = q4.y;
      #pragma unroll
      for (int k = 0; k < 8; ++k) {
        const float2 bo = *(const float2*)(Brow + 2 * k);   // = {P[s*+2k+1], P[s*+2k+2]}
        XP[2*k + 1].x = bo.x; XP[2*k + 1].y = bo.y;
      }
      #pragma unroll
      for (int p = 0; p < 7; ++p) {
        Z1[p] = fma2(W1, XP[2*p + 2], Z1[p]);
        Z2[p] = fma2(W2[0], XP[2*p + 1], Z2[p]);
        Z2[p] = fma2(W2[1], XP[2*p + 2], Z2[p]);
        Z2[p] = fma2(W2[2], XP[2*p + 3], Z2[p]);
        Z3[p] = fma2(W3[0], XP[2*p    ], Z3[p]);
        Z3[p] = fma2(W3[1], XP[2*p + 1], Z3[p]);
        Z3[p] = fma2(W3[2], XP[2*p + 2], Z3[p]);
        Z3[p] = fma2(W3[3], XP[2*p + 3], Z3[p]);
        Z3[p] = fma2(W3[4], XP[2*p + 4], Z3[p]);
      }
    }
    const float b1v = c1b[o], b2v = c2b[o], b3v = c3b[o];
    float a1 = 0.0f, a2 = 0.0f, a3 = 0.0f;
    // Gather index algebra: f = o*50+l (+800/+1600); col = (2o+l)&15;
    // r1 = o+(t>=48); r2 = 16+o+(t>=16)+(t>=64); r3 = 33+o+(t>=32); t=2o+l.
    auto body = [&](const int u) {
      const int l = s + u;
      const int t = 2 * o + l;
      const int col = t & 15;
      const int r1 = o + ((t >= 48) ? 1 : 0);
      const int r2 = 16 + o + ((t >= 16) ? 1 : 0) + ((t >= 64) ? 1 : 0);
      const int r3 = 33 + o + ((t >= 32) ? 1 : 0);
      float v1 = lrelu(Z1[u >> 1][u & 1] + b1v);
      float v2 = lrelu(Z2[u >> 1][u & 1] + b2v);
      float v3 = lrelu(Z3[u >> 1][u & 1] + b3v);
      a1 += v1 * sATt[col * 52 + r1];
      a2 += v2 * sATt[col * 52 + r2];
      a3 += v3 * sATt[col * 52 + r3];
    };
    #pragma unroll
    for (int u = 0; u < 12; ++u) body(u);
    if (seg == 3) { body(12); body(13); }   // exec-masked tail, lanes 48-63 only
    a1 += __shfl_xor(a1, 16); a1 += __shfl_xor(a1, 32);
    a2 += __shfl_xor(a2, 16); a2 += __shfl_xor(a2, 32);
    a3 += __shfl_xor(a3, 16); a3 += __shfl_xor(a3, 32);
    if (lane < CHN) { sFE[o] = a1; sFE[CHN + o] = a2; sFE[2 * CHN + o] = a3; }
  }
  WAVE_FENCE();      // sFE conv part done; sATt dead -> sC may overwrite

  // ---- Phase 6a: T rows + column normalizers; sC[j] = {T[0..5], -, WX[8..13]} ----
  // XOR-swizzled rows: addr(r,c) = r*16 + (c ^ xw(r)), xw(r) = ((r>>1)&3)<<2.
  float* sC = R1;
  vf2 ri2[3];
  if (lane < LSEQ) {
    const int xw = ((lane >> 1) & 3) << 2;
    float* rp = sC + lane * 16;
    float colj[HID];
    #pragma unroll
    for (int h = 0; h < HID; ++h) colj[h] = sX4[h * LSEQ + lane];   // reshape view
    vf2 cj2[3];
    #pragma unroll
    for (int p = 0; p < 3; ++p) { cj2[p].x = colj[2*p]; cj2[p].y = colj[2*p+1]; }
    *(float4*)(rp + xw)       = make_float4(colj[0], colj[1], colj[2], colj[3]);
    *(float2*)(rp + (4 ^ xw)) = make_float2(colj[4], colj[5]);
    float zs0 = 0.0f, zs1 = 0.0f;
    #pragma unroll
    for (int i = 0; i < LSEQ; i += 2) {
      const float2 r0 = *(const float2*)(sX4 + i * 6);
      const float2 r1 = *(const float2*)(sX4 + i * 6 + 2);
      const float2 r2 = *(const float2*)(sX4 + i * 6 + 4);
      vf2 s2 = (vf2)0.0f;
      vf2 p0; p0.x = r0.x; p0.y = r0.y;
      vf2 p1; p1.x = r1.x; p1.y = r1.y;
      vf2 p2; p2.x = r2.x; p2.y = r2.y;
      s2 = fma2(p0, cj2[0], s2);
      s2 = fma2(p1, cj2[1], s2);
      s2 = fma2(p2, cj2[2], s2);
      zs0 += fexp2((s2.x + s2.y) * KEXP);
      const float2 t0 = *(const float2*)(sX4 + (i + 1) * 6);
      const float2 t1 = *(const float2*)(sX4 + (i + 1) * 6 + 2);
      const float2 t2 = *(const float2*)(sX4 + (i + 1) * 6 + 4);
      vf2 u2 = (vf2)0.0f;
      vf2 v0; v0.x = t0.x; v0.y = t0.y;
      vf2 v1; v1.x = t1.x; v1.y = t1.y;
      vf2 v2; v2.x = t2.x; v2.y = t2.y;
      u2 = fma2(v0, cj2[0], u2);
      u2 = fma2(v1, cj2[1], u2);
      u2 = fma2(v2, cj2[2], u2);
      zs1 += fexp2((u2.x + u2.y) * KEXP);
    }
    const float zi = frcp(zs0 + zs1);
    const float2 q0 = *(const float2*)(sX4 + lane * 6);
    const float2 q1 = *(const float2*)(sX4 + lane * 6 + 2);
    const float2 q2 = *(const float2*)(sX4 + lane * 6 + 4);
    ri2[0].x = q0.x; ri2[0].y = q0.y;
    ri2[1].x = q1.x; ri2[1].y = q1.y;
    ri2[2].x = q2.x; ri2[2].y = q2.y;
    *(float4*)(rp + (8 ^ xw))  = make_float4(zi*q0.x, zi*q0.y, zi*q1.x, zi*q1.y);
    *(float2*)(rp + (12 ^ xw)) = make_float2(zi*q2.x, zi*q2.y);
  }
  WAVE_FENCE();      // sC rows -> phase 6b (cross-lane)

  // ---- Phase 6b: y0[i][h] = sum_j exp(s[i,j]/6) * WX[j][h] (ri2 kept in regs) ----
  if (lane < LSEQ) {
    vf2 ya2[3];
    #pragma unroll
    for (int p = 0; p < 3; ++p) ya2[p] = (vf2)0.0f;
    auto acc_row = [&](const float* rp, const int xw) {
      const float4 t0 = *(const float4*)(rp + xw);          // cols 0-3
      const float2 t1 = *(const float2*)(rp + (4 ^ xw));    // cols 4-5
      vf2 p0; p0.x = t0.x; p0.y = t0.y;
      vf2 p1; p1.x = t0.z; p1.y = t0.w;
      vf2 p2; p2.x = t1.x; p2.y = t1.y;
      vf2 s2 = (vf2)0.0f;
      s2 = fma2(ri2[0], p0, s2);
      s2 = fma2(ri2[1], p1, s2);
      s2 = fma2(ri2[2], p2, s2);
      const float e = fexp2((s2.x + s2.y) * KEXP);
      vf2 e2; e2.x = e; e2.y = e;
      const float4 w0 = *(const float4*)(rp + (8 ^ xw));    // cols 8-11
      const float2 w1 = *(const float2*)(rp + (12 ^ xw));   // cols 12-13
      vf2 wv0; wv0.x = w0.x; wv0.y = w0.y;
      vf2 wv1; wv1.x = w0.z; wv1.y = w0.w;
      vf2 wv2; wv2.x = w1.x; wv2.y = w1.y;
      ya2[0] = fma2(e2, wv0, ya2[0]);
      ya2[1] = fma2(e2, wv1, ya2[1]);
      ya2[2] = fma2(e2, wv2, ya2[2]);
    };
    for (int jb = 0; jb < 48; jb += 8) {
      const float* cp = sC + jb * 16;
      #pragma unroll
      for (int d = 0; d < 8; ++d) acc_row(cp + d * 16, ((d >> 1) & 3) << 2);
    }
    acc_row(sC + 48 * 16, 0);   // j=48: xw(48)=0
    acc_row(sC + 49 * 16, 0);   // j=49: xw(49)=0
    *(float2*)(sY + lane * 6)     = make_float2(ya2[0].x, ya2[0].y);
    *(float2*)(sY + lane * 6 + 2) = make_float2(ya2[1].x, ya2[1].y);
    *(float2*)(sY + lane * 6 + 4) = make_float2(ya2[2].x, ya2[2].y);
  }
  WAVE_FENCE();      // sY -> phase 7 (cross-lane)

  // ---- Phase 7: x_gru — 48 lanes (8 per h) + shfl reduce ----
  if (lane < 48) {
    const int h = lane >> 3;
    const int m = lane & 7;
    float s = 0.0f;
    #pragma unroll
    for (int k = 0; k < 7; ++k) {
      const int idx = m + (k << 3);
      if (idx < LSEQ) s += sY[h * LSEQ + idx];
    }
    s += __shfl_xor(s, 1);
    s += __shfl_xor(s, 2);
    s += __shfl_xor(s, 4);
    if (m == 0) sFE[48 + h] = s;
  }
  WAVE_FENCE();      // sFE complete -> phase 8

  // ---- Phase 8: fc — 64 lanes (32 per output) + shfl reduce ----
  {
    const int oo = lane & 1;
    const int kk = lane >> 1;
    float s = fc3w[oo * 54 + kk] * sFE[kk];
    if (kk < 22) s = fmaf(fc3w[oo * 54 + kk + 32], sFE[kk + 32], s);
    s += __shfl_xor(s, 2);
    s += __shfl_xor(s, 4);
    s += __shfl_xor(s, 8);
    s += __shfl_xor(s, 16);
    s += __shfl_xor(s, 32);
    if (lane < 2) out[(size_t)b * 2 + lane] = s + fc3b[lane];
  }
}

extern "C" void kernel_launch(void* const* d_in, const int* in_sizes, int n_in,
                              void* d_out, int out_size, void* d_ws, size_t ws_size,
                              hipStream_t stream) {
  (void)in_sizes; (void)n_in; (void)d_ws; (void)ws_size; (void)out_size;
  fused_kernel<<<BATCH, 64, 0, stream>>>(
      (const float*)d_in[0],
      (const float*)d_in[1],  (const float*)d_in[2],
      (const float*)d_in[3],  (const float*)d_in[4],
      (const float*)d_in[5],  (const float*)d_in[6],
      (const float*)d_in[7],  (const float*)d_in[8],
      (const float*)d_in[9],  (const float*)d_in[10],
      (const float*)d_in[11], (const float*)d_in[12],
      (const float*)d_in[13], (const float*)d_in[14],
      (const float*)d_in[15], (const float*)d_in[16],
      (float*)d_out);
}

// Round 8
// 280.478 us; speedup vs baseline: 1.0226x; 1.0226x over previous
//
#include <hip/hip_runtime.h>

#define BATCH 16384
#define LSEQ  50
#define DIN   20
#define CHN   16
#define HID   6

typedef float vf2 __attribute__((ext_vector_type(2)));

__device__ __forceinline__ float frcp(float x){ return __builtin_amdgcn_rcpf(x); }
__device__ __forceinline__ float fexp2(float x){
#if __has_builtin(__builtin_amdgcn_exp2f)
  return __builtin_amdgcn_exp2f(x);
#else
  return exp2f(x);
#endif
}
// exp(x) = 2^(x*log2e); constants pre-folded to keep one v_mul + one v_exp per call
#define LOG2E 1.4426950408889634f
__device__ __forceinline__ float fsig(float x){ return frcp(1.0f + fexp2(-LOG2E * x)); }
__device__ __forceinline__ float ftanh(float x){ float t = fexp2((2.0f*LOG2E)*x); return (t - 1.0f) * frcp(t + 1.0f); }
__device__ __forceinline__ float lrelu(float v){ return v > 0.0f ? v : 0.1f*v; }
__device__ __forceinline__ vf2 fma2(vf2 a, vf2 b, vf2 c){
#if __has_builtin(__builtin_elementwise_fma)
  return __builtin_elementwise_fma(a, b, c);
#else
  vf2 r; r.x = fmaf(a.x, b.x, c.x); r.y = fmaf(a.y, b.y, c.y); return r;
#endif
}
// exp(s/6) = 2^(s * log2e/6)
#define KEXP 0.24044917348149793f

// uniform broadcast of lane l's value (SALU path, ignores exec mask)
__device__ __forceinline__ float readlane_f(float v, int l){
  return __int_as_float(__builtin_amdgcn_readlane(__float_as_int(v), l));
}

// Intra-wave LDS ordering fence (cross-lane deps within the single wave).
#define WAVE_FENCE() asm volatile("s_waitcnt lgkmcnt(0)" ::: "memory")

// Single-wave block; per-block LDS slab, SLAB = 2040 floats = 8160 B.
// (Occupancy cap calibrated in r7: min(~13.8 waves/CU, LDS-limit). Keep
//  LDS/wave <= 8KB so the LDS limit stays above the cap.)
//  [0,840)     sXEp: padded conv rows, stride 52: P[i][2+m] = xe_flat[i*50+m].
//              sY aliases [0,300) (live after conv phase is done).
//  [840,1740)  gi rows [50][18] in TRIPLET order: [l][3h+{r,z,n}]. After GRU:
//                sATt [16][52] in [840,1672)  (transposed attn)
//                sFE  at [1672,1726)          (dead gi tail)
//                sC   [50][16] XOR-swizzled in [840,1640)
//  [1740,2040) sX4: x4 flat (l*6+h)
constexpr int SLAB = 2040;

__global__ __launch_bounds__(64, 4) void fused_kernel(
    const float* __restrict__ x,
    const float* __restrict__ we_w, const float* __restrict__ we_b,
    const float* __restrict__ attn_w, const float* __restrict__ attn_b,
    const float* __restrict__ c1w, const float* __restrict__ c1b,
    const float* __restrict__ c2w, const float* __restrict__ c2b,
    const float* __restrict__ c3w, const float* __restrict__ c3b,
    const float* __restrict__ wih, const float* __restrict__ whh,
    const float* __restrict__ bih, const float* __restrict__ bhh,
    const float* __restrict__ fc3w, const float* __restrict__ fc3b,
    float* __restrict__ out)
{
  __shared__ __align__(16) float smem[SLAB];
  const int lane = threadIdx.x;   // 64 threads = 1 wave
  const int b    = blockIdx.x;

  float* S    = smem;
  float* sXEp = S;
  float* sY   = S;          // alias, live after conv
  float* R1   = S + 840;    // gi -> sATt/sC
  float* sFE  = S + 1672;   // R1 + 832
  float* sX4  = S + 1740;

  const float* xb = x + (size_t)b * (LSEQ * DIN);

  // ---- zero the shared row pads ----
  if (lane < CHN) {
    sXEp[lane * 52]     = 0.0f;
    sXEp[lane * 52 + 1] = 0.0f;
  } else if (lane == 16) {
    sXEp[832] = 0.0f;
    sXEp[833] = 0.0f;
  }

  // ---- Phase 1+3: lane l computes xe[l][0..15] (scatter to padded rows) and gi[l][0..17] ----
  if (lane < LSEQ) {
    vf2 xv2[10];
    const float4* xr = (const float4*)(xb + lane * DIN);
    #pragma unroll
    for (int q = 0; q < 5; ++q) {
      float4 v = xr[q];
      vf2 p0; p0.x = v.x; p0.y = v.y;
      vf2 p1; p1.x = v.z; p1.y = v.w;
      xv2[2*q] = p0; xv2[2*q+1] = p1;
    }
    float xe[CHN];
    #pragma unroll
    for (int c = 0; c < CHN; ++c) {
      const vf2* wr = (const vf2*)(we_w + c * DIN);
      vf2 a2; a2.x = we_b[c]; a2.y = 0.0f;
      #pragma unroll
      for (int dp = 0; dp < 10; ++dp) a2 = fma2(xv2[dp], wr[dp], a2);
      xe[c] = a2.x + a2.y;
    }
    // scatter: kk = 16*lane + c ; i = kk/50, m = kk%50 ; addr = 52i + 2 + m
    const int kk0 = lane * CHN;
    const int i0  = kk0 / 50;
    const int m0  = kk0 - i0 * 50;
    float* basep = sXEp + i0 * 52 + 2 + m0;
    #pragma unroll
    for (int c = 0; c < CHN; ++c) {
      const int off = c + ((m0 + c >= 50) ? 2 : 0);
      basep[off] = xe[c];
    }
    vf2 xe2[8];
    #pragma unroll
    for (int p = 0; p < 8; ++p) { xe2[p].x = xe[2*p]; xe2[p].y = xe[2*p+1]; }
    float gi[18];
    #pragma unroll
    for (int g = 0; g < 18; ++g) {
      const vf2* wr = (const vf2*)(wih + g * CHN);
      vf2 a2; a2.x = bih[g]; a2.y = 0.0f;
      #pragma unroll
      for (int p = 0; p < 8; ++p) a2 = fma2(xe2[p], wr[p], a2);
      gi[g] = a2.x + a2.y;
    }
    // TRIPLET store: flat[f] = gi[(f%3)*6 + f/3]  ->  lane h reads (r,z,n) at 3h
    float2* gd = (float2*)(R1 + lane * 18);
    gd[0] = make_float2(gi[0],  gi[6]);
    gd[1] = make_float2(gi[12], gi[1]);
    gd[2] = make_float2(gi[7],  gi[13]);
    gd[3] = make_float2(gi[2],  gi[8]);
    gd[4] = make_float2(gi[14], gi[3]);
    gd[5] = make_float2(gi[9],  gi[15]);
    gd[6] = make_float2(gi[4],  gi[10]);
    gd[7] = make_float2(gi[16], gi[5]);
    gd[8] = make_float2(gi[11], gi[17]);
  }
  WAVE_FENCE();      // gi + sXEp ready (cross-lane within this wave)

  // ---- Phase 4: GRU — zero-shuffle 6-lane form with REGISTER h-broadcast:
  // v_readlane (SALU, ignores exec) replaces the LDS write->read round-trip
  // on the recurrence chain. sX4 store stays but is off-chain (consumed only
  // after the phase fence). Same fma pairing -> identical numerics.
  // Triplet base R1+3h is only 4B-aligned for odd h -> SCALAR gi loads only.
  if (lane < HID) {
    const int h = lane;
    vf2 wr2[3], wz2[3], wn2[3];
    #pragma unroll
    for (int k = 0; k < 3; ++k) {
      const float2 a = *(const float2*)(whh + h        * HID + 2*k);
      const float2 c = *(const float2*)(whh + (6 + h)  * HID + 2*k);
      const float2 d = *(const float2*)(whh + (12 + h) * HID + 2*k);
      wr2[k].x = a.x; wr2[k].y = a.y;
      wz2[k].x = c.x; wz2[k].y = c.y;
      wn2[k].x = d.x; wn2[k].y = d.y;
    }
    const float br = bhh[h], bz = bhh[6 + h], bn = bhh[12 + h];

    vf2 hh2[3];
    #pragma unroll
    for (int k = 0; k < 3; ++k) hh2[k] = (vf2)0.0f;
    float hprev = 0.0f;

    // software-pipelined gi reads (l=49 prefetch lands in sX4 region: junk, unused)
    const float* gp = R1 + 3 * h;
    float gR = gp[0];
    float gZ = gp[1];
    float gN = gp[2];
    for (int l = 0; l < LSEQ; ++l) {
      const float gir = gR, giz = gZ, gin = gN;
      gp += 18;
      gR = gp[0];
      gZ = gp[1];
      gN = gp[2];
      vf2 ar; ar.x = br; ar.y = 0.0f;
      vf2 az; az.x = bz; az.y = 0.0f;
      vf2 an; an.x = bn; an.y = 0.0f;
      #pragma unroll
      for (int k = 0; k < 3; ++k) {
        ar = fma2(wr2[k], hh2[k], ar);
        az = fma2(wz2[k], hh2[k], az);
        an = fma2(wn2[k], hh2[k], an);
      }
      const float dr = ar.x + ar.y;
      const float dz = az.x + az.y;
      const float dn = an.x + an.y;
      const float r  = fsig(gir + dr);
      const float z  = fsig(giz + dz);
      const float n  = ftanh(fmaf(r, dn, gin));
      const float hn = fmaf(z, hprev - n, n);
      hprev = hn;
      sX4[l * HID + h] = hn;      // off-chain; visibility via phase fence
      const float h0 = readlane_f(hn, 0);
      const float h1 = readlane_f(hn, 1);
      const float h2 = readlane_f(hn, 2);
      const float h3 = readlane_f(hn, 3);
      const float h4 = readlane_f(hn, 4);
      const float h5 = readlane_f(hn, 5);
      hh2[0].x = h0; hh2[0].y = h1;
      hh2[1].x = h2; hh2[1].y = h3;
      hh2[2].x = h4; hh2[2].y = h5;
    }
  }
  WAVE_FENCE();      // x4 ready; gi dead (sATt may overwrite)

  // ---- Phase 2: attn rows -> TRANSPOSED sATt[16][52] (conflict-free b32 writes) ----
  // attn input is the RESHAPE view xe_flat[c*50+l] -> LDS gather is mandatory.
  {
    float* sATt = R1;
    if (lane < LSEQ) {
      float a[CHN];
      #pragma unroll
      for (int cc = 0; cc < CHN; ++cc) a[cc] = sXEp[cc * 52 + 2 + lane];  // reshape view
      vf2 a2[8];
      #pragma unroll
      for (int p = 0; p < 8; ++p) { a2[p].x = a[2*p]; a2[p].y = a[2*p+1]; }
      #pragma unroll
      for (int c = 0; c < CHN; ++c) {
        const vf2* wr = (const vf2*)(attn_w + c * CHN);
        vf2 s2; s2.x = attn_b[c]; s2.y = 0.0f;
        #pragma unroll
        for (int p = 0; p < 8; ++p) s2 = fma2(a2[p], wr[p], s2);
        sATt[c * 52 + lane] = ftanh(s2.x + s2.y);
      }
    }
  }
  WAVE_FENCE();      // sATt -> conv

  // ---- Phase 5: convs (b128 LDS loads, packed-pair taps) fused with attn1 reduction ----
  {
    const float* sATt = R1;
    const int o   = lane & 15;
    const int seg = lane >> 4;
    const int s   = seg * 12;
    vf2 Z1[7], Z2[7], Z3[7];
    #pragma unroll
    for (int p = 0; p < 7; ++p) {
      Z1[p] = (vf2)0.0f; Z2[p] = (vf2)0.0f; Z3[p] = (vf2)0.0f;
    }
    for (int i = 0; i < CHN; ++i) {
      const float w1s = c1w[o * CHN + i];
      vf2 W1; W1.x = w1s; W1.y = w1s;
      vf2 W2[3], W3[5];
      #pragma unroll
      for (int t = 0; t < 3; ++t) { float w = c2w[(o * CHN + i) * 3 + t]; W2[t].x = w; W2[t].y = w; }
      #pragma unroll
      for (int t = 0; t < 5; ++t) { float w = c3w[(o * CHN + i) * 5 + t]; W3[t].x = w; W3[t].y = w; }
      const float4* wp = (const float4*)(sXEp + i * 52 + s);
      float4 q0 = wp[0], q1 = wp[1], q2 = wp[2], q3 = wp[3], q4 = wp[4];
      float xv[20] = {q0.x,q0.y,q0.z,q0.w, q1.x,q1.y,q1.z,q1.w,
                      q2.x,q2.y,q2.z,q2.w, q3.x,q3.y,q3.z,q3.w,
                      q4.x,q4.y,q4.z,q4.w};
      vf2 XP[17];
      #pragma unroll
      for (int a = 0; a < 17; ++a) { XP[a].x = xv[a]; XP[a].y = xv[a+1]; }
      #pragma unroll
      for (int p = 0; p < 7; ++p) {
        Z1[p] = fma2(W1, XP[2*p + 2], Z1[p]);
        Z2[p] = fma2(W2[0], XP[2*p + 1], Z2[p]);
        Z2[p] = fma2(W2[1], XP[2*p + 2], Z2[p]);
        Z2[p] = fma2(W2[2], XP[2*p + 3], Z2[p]);
        Z3[p] = fma2(W3[0], XP[2*p    ], Z3[p]);
        Z3[p] = fma2(W3[1], XP[2*p + 1], Z3[p]);
        Z3[p] = fma2(W3[2], XP[2*p + 2], Z3[p]);
        Z3[p] = fma2(W3[3], XP[2*p + 3], Z3[p]);
        Z3[p] = fma2(W3[4], XP[2*p + 4], Z3[p]);
      }
    }
    const float b1v = c1b[o], b2v = c2b[o], b3v = c3b[o];
    float a1 = 0.0f, a2 = 0.0f, a3 = 0.0f;
    // Gather index algebra: f = o*50+l (+800/+1600); col = (2o+l)&15;
    // r1 = o+(t>=48); r2 = 16+o+(t>=16)+(t>=64); r3 = 33+o+(t>=32); t=2o+l.
    auto body = [&](const int u) {
      const int l = s + u;
      const int t = 2 * o + l;
      const int col = t & 15;
      const int r1 = o + ((t >= 48) ? 1 : 0);
      const int r2 = 16 + o + ((t >= 16) ? 1 : 0) + ((t >= 64) ? 1 : 0);
      const int r3 = 33 + o + ((t >= 32) ? 1 : 0);
      float v1 = lrelu(Z1[u >> 1][u & 1] + b1v);
      float v2 = lrelu(Z2[u >> 1][u & 1] + b2v);
      float v3 = lrelu(Z3[u >> 1][u & 1] + b3v);
      a1 += v1 * sATt[col * 52 + r1];
      a2 += v2 * sATt[col * 52 + r2];
      a3 += v3 * sATt[col * 52 + r3];
    };
    #pragma unroll
    for (int u = 0; u < 12; ++u) body(u);
    if (seg == 3) { body(12); body(13); }   // exec-masked tail, lanes 48-63 only
    a1 += __shfl_xor(a1, 16); a1 += __shfl_xor(a1, 32);
    a2 += __shfl_xor(a2, 16); a2 += __shfl_xor(a2, 32);
    a3 += __shfl_xor(a3, 16); a3 += __shfl_xor(a3, 32);
    if (lane < CHN) { sFE[o] = a1; sFE[CHN + o] = a2; sFE[2 * CHN + o] = a3; }
  }
  WAVE_FENCE();      // sFE conv part done; sATt dead -> sC may overwrite

  // ---- Phase 6a: T rows + column normalizers; sC[j] = {T[0..5], -, WX[8..13]} ----
  // XOR-swizzled rows: addr(r,c) = r*16 + (c ^ xw(r)), xw(r) = ((r>>1)&3)<<2.
  float* sC = R1;
  vf2 ri2[3];
  if (lane < LSEQ) {
    const int xw = ((lane >> 1) & 3) << 2;
    float* rp = sC + lane * 16;
    float colj[HID];
    #pragma unroll
    for (int h = 0; h < HID; ++h) colj[h] = sX4[h * LSEQ + lane];   // reshape view
    vf2 cj2[3];
    #pragma unroll
    for (int p = 0; p < 3; ++p) { cj2[p].x = colj[2*p]; cj2[p].y = colj[2*p+1]; }
    *(float4*)(rp + xw)       = make_float4(colj[0], colj[1], colj[2], colj[3]);
    *(float2*)(rp + (4 ^ xw)) = make_float2(colj[4], colj[5]);
    float zs0 = 0.0f, zs1 = 0.0f;
    #pragma unroll
    for (int i = 0; i < LSEQ; i += 2) {
      const float2 r0 = *(const float2*)(sX4 + i * 6);
      const float2 r1 = *(const float2*)(sX4 + i * 6 + 2);
      const float2 r2 = *(const float2*)(sX4 + i * 6 + 4);
      vf2 s2 = (vf2)0.0f;
      vf2 p0; p0.x = r0.x; p0.y = r0.y;
      vf2 p1; p1.x = r1.x; p1.y = r1.y;
      vf2 p2; p2.x = r2.x; p2.y = r2.y;
      s2 = fma2(p0, cj2[0], s2);
      s2 = fma2(p1, cj2[1], s2);
      s2 = fma2(p2, cj2[2], s2);
      zs0 += fexp2((s2.x + s2.y) * KEXP);
      const float2 t0 = *(const float2*)(sX4 + (i + 1) * 6);
      const float2 t1 = *(const float2*)(sX4 + (i + 1) * 6 + 2);
      const float2 t2 = *(const float2*)(sX4 + (i + 1) * 6 + 4);
      vf2 u2 = (vf2)0.0f;
      vf2 v0; v0.x = t0.x; v0.y = t0.y;
      vf2 v1; v1.x = t1.x; v1.y = t1.y;
      vf2 v2; v2.x = t2.x; v2.y = t2.y;
      u2 = fma2(v0, cj2[0], u2);
      u2 = fma2(v1, cj2[1], u2);
      u2 = fma2(v2, cj2[2], u2);
      zs1 += fexp2((u2.x + u2.y) * KEXP);
    }
    const float zi = frcp(zs0 + zs1);
    const float2 q0 = *(const float2*)(sX4 + lane * 6);
    const float2 q1 = *(const float2*)(sX4 + lane * 6 + 2);
    const float2 q2 = *(const float2*)(sX4 + lane * 6 + 4);
    ri2[0].x = q0.x; ri2[0].y = q0.y;
    ri2[1].x = q1.x; ri2[1].y = q1.y;
    ri2[2].x = q2.x; ri2[2].y = q2.y;
    *(float4*)(rp + (8 ^ xw))  = make_float4(zi*q0.x, zi*q0.y, zi*q1.x, zi*q1.y);
    *(float2*)(rp + (12 ^ xw)) = make_float2(zi*q2.x, zi*q2.y);
  }
  WAVE_FENCE();      // sC rows -> phase 6b (cross-lane)

  // ---- Phase 6b: y0[i][h] = sum_j exp(s[i,j]/6) * WX[j][h] (ri2 kept in regs) ----
  if (lane < LSEQ) {
    vf2 ya2[3];
    #pragma unroll
    for (int p = 0; p < 3; ++p) ya2[p] = (vf2)0.0f;
    auto acc_row = [&](const float* rp, const int xw) {
      const float4 t0 = *(const float4*)(rp + xw);          // cols 0-3
      const float2 t1 = *(const float2*)(rp + (4 ^ xw));    // cols 4-5
      vf2 p0; p0.x = t0.x; p0.y = t0.y;
      vf2 p1; p1.x = t0.z; p1.y = t0.w;
      vf2 p2; p2.x = t1.x; p2.y = t1.y;
      vf2 s2 = (vf2)0.0f;
      s2 = fma2(ri2[0], p0, s2);
      s2 = fma2(ri2[1], p1, s2);
      s2 = fma2(ri2[2], p2, s2);
      const float e = fexp2((s2.x + s2.y) * KEXP);
      vf2 e2; e2.x = e; e2.y = e;
      const float4 w0 = *(const float4*)(rp + (8 ^ xw));    // cols 8-11
      const float2 w1 = *(const float2*)(rp + (12 ^ xw));   // cols 12-13
      vf2 wv0; wv0.x = w0.x; wv0.y = w0.y;
      vf2 wv1; wv1.x = w0.z; wv1.y = w0.w;
      vf2 wv2; wv2.x = w1.x; wv2.y = w1.y;
      ya2[0] = fma2(e2, wv0, ya2[0]);
      ya2[1] = fma2(e2, wv1, ya2[1]);
      ya2[2] = fma2(e2, wv2, ya2[2]);
    };
    for (int jb = 0; jb < 48; jb += 8) {
      const float* cp = sC + jb * 16;
      #pragma unroll
      for (int d = 0; d < 8; ++d) acc_row(cp + d * 16, ((d >> 1) & 3) << 2);
    }
    acc_row(sC + 48 * 16, 0);   // j=48: xw(48)=0
    acc_row(sC + 49 * 16, 0);   // j=49: xw(49)=0
    *(float2*)(sY + lane * 6)     = make_float2(ya2[0].x, ya2[0].y);
    *(float2*)(sY + lane * 6 + 2) = make_float2(ya2[1].x, ya2[1].y);
    *(float2*)(sY + lane * 6 + 4) = make_float2(ya2[2].x, ya2[2].y);
  }
  WAVE_FENCE();      // sY -> phase 7 (cross-lane)

  // ---- Phase 7: x_gru — 48 lanes (8 per h) + shfl reduce ----
  if (lane < 48) {
    const int h = lane >> 3;
    const int m = lane & 7;
    float s = 0.0f;
    #pragma unroll
    for (int k = 0; k < 7; ++k) {
      const int idx = m + (k << 3);
      if (idx < LSEQ) s += sY[h * LSEQ + idx];
    }
    s += __shfl_xor(s, 1);
    s += __shfl_xor(s, 2);
    s += __shfl_xor(s, 4);
    if (m == 0) sFE[48 + h] = s;
  }
  WAVE_FENCE();      // sFE complete -> phase 8

  // ---- Phase 8: fc — 64 lanes (32 per output) + shfl reduce ----
  {
    const int oo = lane & 1;
    const int kk = lane >> 1;
    float s = fc3w[oo * 54 + kk] * sFE[kk];
    if (kk < 22) s = fmaf(fc3w[oo * 54 + kk + 32], sFE[kk + 32], s);
    s += __shfl_xor(s, 2);
    s += __shfl_xor(s, 4);
    s += __shfl_xor(s, 8);
    s += __shfl_xor(s, 16);
    s += __shfl_xor(s, 32);
    if (lane < 2) out[(size_t)b * 2 + lane] = s + fc3b[lane];
  }
}

extern "C" void kernel_launch(void* const* d_in, const int* in_sizes, int n_in,
                              void* d_out, int out_size, void* d_ws, size_t ws_size,
                              hipStream_t stream) {
  (void)in_sizes; (void)n_in; (void)d_ws; (void)ws_size; (void)out_size;
  fused_kernel<<<BATCH, 64, 0, stream>>>(
      (const float*)d_in[0],
      (const float*)d_in[1],  (const float*)d_in[2],
      (const float*)d_in[3],  (const float*)d_in[4],
      (const float*)d_in[5],  (const float*)d_in[6],
      (const float*)d_in[7],  (const float*)d_in[8],
      (const float*)d_in[9],  (const float*)d_in[10],
      (const float*)d_in[11], (const float*)d_in[12],
      (const float*)d_in[13], (const float*)d_in[14],
      (const float*)d_in[15], (const float*)d_in[16],
      (float*)d_out);
}

// Round 9
// 274.497 us; speedup vs baseline: 1.0449x; 1.0218x over previous
//
#include <hip/hip_runtime.h>

#define BATCH 16384
#define LSEQ  50
#define DIN   20
#define CHN   16
#define HID   6

typedef float vf2 __attribute__((ext_vector_type(2)));

__device__ __forceinline__ float frcp(float x){ return __builtin_amdgcn_rcpf(x); }
__device__ __forceinline__ float fexp2(float x){
#if __has_builtin(__builtin_amdgcn_exp2f)
  return __builtin_amdgcn_exp2f(x);
#else
  return exp2f(x);
#endif
}
// exp(x) = 2^(x*log2e); constants pre-folded to keep one v_mul + one v_exp per call
#define LOG2E 1.4426950408889634f
__device__ __forceinline__ float fsig(float x){ return frcp(1.0f + fexp2(-LOG2E * x)); }
__device__ __forceinline__ float ftanh(float x){ float t = fexp2((2.0f*LOG2E)*x); return (t - 1.0f) * frcp(t + 1.0f); }
__device__ __forceinline__ float lrelu(float v){ return v > 0.0f ? v : 0.1f*v; }
__device__ __forceinline__ vf2 fma2(vf2 a, vf2 b, vf2 c){
#if __has_builtin(__builtin_elementwise_fma)
  return __builtin_elementwise_fma(a, b, c);
#else
  vf2 r; r.x = fmaf(a.x, b.x, c.x); r.y = fmaf(a.y, b.y, c.y); return r;
#endif
}
// exp(s/6) = 2^(s * log2e/6)
#define KEXP 0.24044917348149793f

// Intra-wave LDS ordering fence (cross-lane deps within the single wave).
#define WAVE_FENCE() asm volatile("s_waitcnt lgkmcnt(0)" ::: "memory")

// Single-wave block; per-block LDS slab, SLAB = 2040 floats = 8160 B.
// Session-calibrated constraints (r2..r8):
//  - occupancy cap = min(~13.8 waves/CU, LDS limit): keep LDS/wave <= 8KB (r7)
//  - GRU h-broadcast via LDS round-trip beats readlane (r8) and shuffles (r3-5)
//  - sB shifted conv copy loses: +LDS past 8KB + scatter conflicts (r7)
//  [0,840)     sXEp: padded conv rows, stride 52: P[i][2+m] = xe_flat[i*50+m].
//              sY aliases [0,300) (live after conv phase is done).
//  [840,1740)  gi rows [50][18] in TRIPLET order: [l][3h+{r,z,n}]. After GRU:
//                sATt [16][52] in [840,1672)  (transposed attn)
//                sFE  at [1672,1726)          (dead gi tail)
//                sC   [50][16] XOR-swizzled in [840,1640)
//  [1740,2040) sX4: x4 flat (l*6+h); doubles as the GRU h-state broadcast row
constexpr int SLAB = 2040;

__global__ __launch_bounds__(64, 4) void fused_kernel(
    const float* __restrict__ x,
    const float* __restrict__ we_w, const float* __restrict__ we_b,
    const float* __restrict__ attn_w, const float* __restrict__ attn_b,
    const float* __restrict__ c1w, const float* __restrict__ c1b,
    const float* __restrict__ c2w, const float* __restrict__ c2b,
    const float* __restrict__ c3w, const float* __restrict__ c3b,
    const float* __restrict__ wih, const float* __restrict__ whh,
    const float* __restrict__ bih, const float* __restrict__ bhh,
    const float* __restrict__ fc3w, const float* __restrict__ fc3b,
    float* __restrict__ out)
{
  __shared__ __align__(16) float smem[SLAB];
  const int lane = threadIdx.x;   // 64 threads = 1 wave
  const int b    = blockIdx.x;

  float* S    = smem;
  float* sXEp = S;
  float* sY   = S;          // alias, live after conv
  float* R1   = S + 840;    // gi -> sATt/sC
  float* sFE  = S + 1672;   // R1 + 832
  float* sX4  = S + 1740;

  const float* xb = x + (size_t)b * (LSEQ * DIN);

  // ---- zero the shared row pads ----
  if (lane < CHN) {
    sXEp[lane * 52]     = 0.0f;
    sXEp[lane * 52 + 1] = 0.0f;
  } else if (lane == 16) {
    sXEp[832] = 0.0f;
    sXEp[833] = 0.0f;
  }

  // ---- Phase 1+3: lane l computes xe[l][0..15] (scatter to padded rows) and gi[l][0..17] ----
  if (lane < LSEQ) {
    vf2 xv2[10];
    const float4* xr = (const float4*)(xb + lane * DIN);
    #pragma unroll
    for (int q = 0; q < 5; ++q) {
      float4 v = xr[q];
      vf2 p0; p0.x = v.x; p0.y = v.y;
      vf2 p1; p1.x = v.z; p1.y = v.w;
      xv2[2*q] = p0; xv2[2*q+1] = p1;
    }
    float xe[CHN];
    #pragma unroll
    for (int c = 0; c < CHN; ++c) {
      const vf2* wr = (const vf2*)(we_w + c * DIN);
      vf2 a2; a2.x = we_b[c]; a2.y = 0.0f;
      #pragma unroll
      for (int dp = 0; dp < 10; ++dp) a2 = fma2(xv2[dp], wr[dp], a2);
      xe[c] = a2.x + a2.y;
    }
    // scatter: kk = 16*lane + c ; i = kk/50, m = kk%50 ; addr = 52i + 2 + m
    const int kk0 = lane * CHN;
    const int i0  = kk0 / 50;
    const int m0  = kk0 - i0 * 50;
    float* basep = sXEp + i0 * 52 + 2 + m0;
    #pragma unroll
    for (int c = 0; c < CHN; ++c) {
      const int off = c + ((m0 + c >= 50) ? 2 : 0);
      basep[off] = xe[c];
    }
    vf2 xe2[8];
    #pragma unroll
    for (int p = 0; p < 8; ++p) { xe2[p].x = xe[2*p]; xe2[p].y = xe[2*p+1]; }
    float gi[18];
    #pragma unroll
    for (int g = 0; g < 18; ++g) {
      const vf2* wr = (const vf2*)(wih + g * CHN);
      vf2 a2; a2.x = bih[g]; a2.y = 0.0f;
      #pragma unroll
      for (int p = 0; p < 8; ++p) a2 = fma2(xe2[p], wr[p], a2);
      gi[g] = a2.x + a2.y;
    }
    // TRIPLET store: flat[f] = gi[(f%3)*6 + f/3]  ->  lane h reads (r,z,n) at 3h
    float2* gd = (float2*)(R1 + lane * 18);
    gd[0] = make_float2(gi[0],  gi[6]);
    gd[1] = make_float2(gi[12], gi[1]);
    gd[2] = make_float2(gi[7],  gi[13]);
    gd[3] = make_float2(gi[2],  gi[8]);
    gd[4] = make_float2(gi[14], gi[3]);
    gd[5] = make_float2(gi[9],  gi[15]);
    gd[6] = make_float2(gi[4],  gi[10]);
    gd[7] = make_float2(gi[16], gi[5]);
    gd[8] = make_float2(gi[11], gi[17]);
  }
  WAVE_FENCE();      // gi + sXEp ready (cross-lane within this wave)

  // ---- Phase 4: GRU — zero-shuffle 6-lane form. Lane h computes ALL THREE of
  // its gates (h replicated in-lane); the only cross-lane op is the h-broadcast
  // (1 ds_write + 3 ds_read_b64; intra-wave DS ops complete in order). This
  // measured FASTER than v_readlane broadcast (r8: wait-states + s->v moves on
  // the chain) and than shuffle forms (r3-r5).
  // Triplet base R1+3h is only 4B-aligned for odd h -> SCALAR gi loads only.
  if (lane < HID) {
    const int h = lane;
    vf2 wr2[3], wz2[3], wn2[3];
    #pragma unroll
    for (int k = 0; k < 3; ++k) {
      const float2 a = *(const float2*)(whh + h        * HID + 2*k);
      const float2 c = *(const float2*)(whh + (6 + h)  * HID + 2*k);
      const float2 d = *(const float2*)(whh + (12 + h) * HID + 2*k);
      wr2[k].x = a.x; wr2[k].y = a.y;
      wz2[k].x = c.x; wz2[k].y = c.y;
      wn2[k].x = d.x; wn2[k].y = d.y;
    }
    const float br = bhh[h], bz = bhh[6 + h], bn = bhh[12 + h];

    vf2 hh2[3];
    #pragma unroll
    for (int k = 0; k < 3; ++k) hh2[k] = (vf2)0.0f;
    float hprev = 0.0f;

    // software-pipelined gi reads (l=49 prefetch lands in sX4 region: junk, unused)
    const float* gp = R1 + 3 * h;
    float gR = gp[0];
    float gZ = gp[1];
    float gN = gp[2];
    for (int l = 0; l < LSEQ; ++l) {
      const float gir = gR, giz = gZ, gin = gN;
      gp += 18;
      gR = gp[0];
      gZ = gp[1];
      gN = gp[2];
      vf2 ar; ar.x = br; ar.y = 0.0f;
      vf2 az; az.x = bz; az.y = 0.0f;
      vf2 an; an.x = bn; an.y = 0.0f;
      #pragma unroll
      for (int k = 0; k < 3; ++k) {
        ar = fma2(wr2[k], hh2[k], ar);
        az = fma2(wz2[k], hh2[k], az);
        an = fma2(wn2[k], hh2[k], an);
      }
      const float dr = ar.x + ar.y;
      const float dz = az.x + az.y;
      const float dn = an.x + an.y;
      const float r  = fsig(gir + dr);
      const float z  = fsig(giz + dz);
      const float n  = ftanh(fmaf(r, dn, gin));
      const float hn = fmaf(z, hprev - n, n);
      hprev = hn;
      sX4[l * HID + h] = hn;
      // read back h row (in-order DS within the wave; base l*6 floats = 24B aligned)
      const float2 h01 = *(const float2*)(sX4 + l * HID);
      const float2 h23 = *(const float2*)(sX4 + l * HID + 2);
      const float2 h45 = *(const float2*)(sX4 + l * HID + 4);
      hh2[0].x = h01.x; hh2[0].y = h01.y;
      hh2[1].x = h23.x; hh2[1].y = h23.y;
      hh2[2].x = h45.x; hh2[2].y = h45.y;
    }
  }
  WAVE_FENCE();      // x4 ready; gi dead (sATt may overwrite)

  // ---- Phase 2: attn rows -> TRANSPOSED sATt[16][52] (conflict-free b32 writes) ----
  // attn input is the RESHAPE view xe_flat[c*50+l] -> LDS gather is mandatory.
  {
    float* sATt = R1;
    if (lane < LSEQ) {
      float a[CHN];
      #pragma unroll
      for (int cc = 0; cc < CHN; ++cc) a[cc] = sXEp[cc * 52 + 2 + lane];  // reshape view
      vf2 a2[8];
      #pragma unroll
      for (int p = 0; p < 8; ++p) { a2[p].x = a[2*p]; a2[p].y = a[2*p+1]; }
      #pragma unroll
      for (int c = 0; c < CHN; ++c) {
        const vf2* wr = (const vf2*)(attn_w + c * CHN);
        vf2 s2; s2.x = attn_b[c]; s2.y = 0.0f;
        #pragma unroll
        for (int p = 0; p < 8; ++p) s2 = fma2(a2[p], wr[p], s2);
        sATt[c * 52 + lane] = ftanh(s2.x + s2.y);
      }
    }
  }
  WAVE_FENCE();      // sATt -> conv

  // ---- Phase 5: convs (b128 LDS loads, packed-pair taps) fused with attn1 reduction ----
  {
    const float* sATt = R1;
    const int o   = lane & 15;
    const int seg = lane >> 4;
    const int s   = seg * 12;
    vf2 Z1[7], Z2[7], Z3[7];
    #pragma unroll
    for (int p = 0; p < 7; ++p) {
      Z1[p] = (vf2)0.0f; Z2[p] = (vf2)0.0f; Z3[p] = (vf2)0.0f;
    }
    for (int i = 0; i < CHN; ++i) {
      const float w1s = c1w[o * CHN + i];
      vf2 W1; W1.x = w1s; W1.y = w1s;
      vf2 W2[3], W3[5];
      #pragma unroll
      for (int t = 0; t < 3; ++t) { float w = c2w[(o * CHN + i) * 3 + t]; W2[t].x = w; W2[t].y = w; }
      #pragma unroll
      for (int t = 0; t < 5; ++t) { float w = c3w[(o * CHN + i) * 5 + t]; W3[t].x = w; W3[t].y = w; }
      const float4* wp = (const float4*)(sXEp + i * 52 + s);
      float4 q0 = wp[0], q1 = wp[1], q2 = wp[2], q3 = wp[3], q4 = wp[4];
      float xv[20] = {q0.x,q0.y,q0.z,q0.w, q1.x,q1.y,q1.z,q1.w,
                      q2.x,q2.y,q2.z,q2.w, q3.x,q3.y,q3.z,q3.w,
                      q4.x,q4.y,q4.z,q4.w};
      vf2 XP[17];
      #pragma unroll
      for (int a = 0; a < 17; ++a) { XP[a].x = xv[a]; XP[a].y = xv[a+1]; }
      #pragma unroll
      for (int p = 0; p < 7; ++p) {
        Z1[p] = fma2(W1, XP[2*p + 2], Z1[p]);
        Z2[p] = fma2(W2[0], XP[2*p + 1], Z2[p]);
        Z2[p] = fma2(W2[1], XP[2*p + 2], Z2[p]);
        Z2[p] = fma2(W2[2], XP[2*p + 3], Z2[p]);
        Z3[p] = fma2(W3[0], XP[2*p    ], Z3[p]);
        Z3[p] = fma2(W3[1], XP[2*p + 1], Z3[p]);
        Z3[p] = fma2(W3[2], XP[2*p + 2], Z3[p]);
        Z3[p] = fma2(W3[3], XP[2*p + 3], Z3[p]);
        Z3[p] = fma2(W3[4], XP[2*p + 4], Z3[p]);
      }
    }
    const float b1v = c1b[o], b2v = c2b[o], b3v = c3b[o];
    float a1 = 0.0f, a2 = 0.0f, a3 = 0.0f;
    // Gather index algebra: f = o*50+l (+800/+1600); col = (2o+l)&15;
    // r1 = o+(t>=48); r2 = 16+o+(t>=16)+(t>=64); r3 = 33+o+(t>=32); t=2o+l.
    auto body = [&](const int u) {
      const int l = s + u;
      const int t = 2 * o + l;
      const int col = t & 15;
      const int r1 = o + ((t >= 48) ? 1 : 0);
      const int r2 = 16 + o + ((t >= 16) ? 1 : 0) + ((t >= 64) ? 1 : 0);
      const int r3 = 33 + o + ((t >= 32) ? 1 : 0);
      float v1 = lrelu(Z1[u >> 1][u & 1] + b1v);
      float v2 = lrelu(Z2[u >> 1][u & 1] + b2v);
      float v3 = lrelu(Z3[u >> 1][u & 1] + b3v);
      a1 += v1 * sATt[col * 52 + r1];
      a2 += v2 * sATt[col * 52 + r2];
      a3 += v3 * sATt[col * 52 + r3];
    };
    #pragma unroll
    for (int u = 0; u < 12; ++u) body(u);
    if (seg == 3) { body(12); body(13); }   // exec-masked tail, lanes 48-63 only
    a1 += __shfl_xor(a1, 16); a1 += __shfl_xor(a1, 32);
    a2 += __shfl_xor(a2, 16); a2 += __shfl_xor(a2, 32);
    a3 += __shfl_xor(a3, 16); a3 += __shfl_xor(a3, 32);
    if (lane < CHN) { sFE[o] = a1; sFE[CHN + o] = a2; sFE[2 * CHN + o] = a3; }
  }
  WAVE_FENCE();      // sFE conv part done; sATt dead -> sC may overwrite

  // ---- Phase 6a: T rows + column normalizers; sC[j] = {T[0..5], -, WX[8..13]} ----
  // XOR-swizzled rows: addr(r,c) = r*16 + (c ^ xw(r)), xw(r) = ((r>>1)&3)<<2.
  float* sC = R1;
  vf2 ri2[3];
  if (lane < LSEQ) {
    const int xw = ((lane >> 1) & 3) << 2;
    float* rp = sC + lane * 16;
    float colj[HID];
    #pragma unroll
    for (int h = 0; h < HID; ++h) colj[h] = sX4[h * LSEQ + lane];   // reshape view
    vf2 cj2[3];
    #pragma unroll
    for (int p = 0; p < 3; ++p) { cj2[p].x = colj[2*p]; cj2[p].y = colj[2*p+1]; }
    *(float4*)(rp + xw)       = make_float4(colj[0], colj[1], colj[2], colj[3]);
    *(float2*)(rp + (4 ^ xw)) = make_float2(colj[4], colj[5]);
    float zs0 = 0.0f, zs1 = 0.0f;
    #pragma unroll
    for (int i = 0; i < LSEQ; i += 2) {
      const float2 r0 = *(const float2*)(sX4 + i * 6);
      const float2 r1 = *(const float2*)(sX4 + i * 6 + 2);
      const float2 r2 = *(const float2*)(sX4 + i * 6 + 4);
      vf2 s2 = (vf2)0.0f;
      vf2 p0; p0.x = r0.x; p0.y = r0.y;
      vf2 p1; p1.x = r1.x; p1.y = r1.y;
      vf2 p2; p2.x = r2.x; p2.y = r2.y;
      s2 = fma2(p0, cj2[0], s2);
      s2 = fma2(p1, cj2[1], s2);
      s2 = fma2(p2, cj2[2], s2);
      zs0 += fexp2((s2.x + s2.y) * KEXP);
      const float2 t0 = *(const float2*)(sX4 + (i + 1) * 6);
      const float2 t1 = *(const float2*)(sX4 + (i + 1) * 6 + 2);
      const float2 t2 = *(const float2*)(sX4 + (i + 1) * 6 + 4);
      vf2 u2 = (vf2)0.0f;
      vf2 v0; v0.x = t0.x; v0.y = t0.y;
      vf2 v1; v1.x = t1.x; v1.y = t1.y;
      vf2 v2; v2.x = t2.x; v2.y = t2.y;
      u2 = fma2(v0, cj2[0], u2);
      u2 = fma2(v1, cj2[1], u2);
      u2 = fma2(v2, cj2[2], u2);
      zs1 += fexp2((u2.x + u2.y) * KEXP);
    }
    const float zi = frcp(zs0 + zs1);
    const float2 q0 = *(const float2*)(sX4 + lane * 6);
    const float2 q1 = *(const float2*)(sX4 + lane * 6 + 2);
    const float2 q2 = *(const float2*)(sX4 + lane * 6 + 4);
    ri2[0].x = q0.x; ri2[0].y = q0.y;
    ri2[1].x = q1.x; ri2[1].y = q1.y;
    ri2[2].x = q2.x; ri2[2].y = q2.y;
    *(float4*)(rp + (8 ^ xw))  = make_float4(zi*q0.x, zi*q0.y, zi*q1.x, zi*q1.y);
    *(float2*)(rp + (12 ^ xw)) = make_float2(zi*q2.x, zi*q2.y);
  }
  WAVE_FENCE();      // sC rows -> phase 6b (cross-lane)

  // ---- Phase 6b: y0[i][h] = sum_j exp(s[i,j]/6) * WX[j][h] (ri2 kept in regs) ----
  if (lane < LSEQ) {
    vf2 ya2[3];
    #pragma unroll
    for (int p = 0; p < 3; ++p) ya2[p] = (vf2)0.0f;
    auto acc_row = [&](const float* rp, const int xw) {
      const float4 t0 = *(const float4*)(rp + xw);          // cols 0-3
      const float2 t1 = *(const float2*)(rp + (4 ^ xw));    // cols 4-5
      vf2 p0; p0.x = t0.x; p0.y = t0.y;
      vf2 p1; p1.x = t0.z; p1.y = t0.w;
      vf2 p2; p2.x = t1.x; p2.y = t1.y;
      vf2 s2 = (vf2)0.0f;
      s2 = fma2(ri2[0], p0, s2);
      s2 = fma2(ri2[1], p1, s2);
      s2 = fma2(ri2[2], p2, s2);
      const float e = fexp2((s2.x + s2.y) * KEXP);
      vf2 e2; e2.x = e; e2.y = e;
      const float4 w0 = *(const float4*)(rp + (8 ^ xw));    // cols 8-11
      const float2 w1 = *(const float2*)(rp + (12 ^ xw));   // cols 12-13
      vf2 wv0; wv0.x = w0.x; wv0.y = w0.y;
      vf2 wv1; wv1.x = w0.z; wv1.y = w0.w;
      vf2 wv2; wv2.x = w1.x; wv2.y = w1.y;
      ya2[0] = fma2(e2, wv0, ya2[0]);
      ya2[1] = fma2(e2, wv1, ya2[1]);
      ya2[2] = fma2(e2, wv2, ya2[2]);
    };
    for (int jb = 0; jb < 48; jb += 8) {
      const float* cp = sC + jb * 16;
      #pragma unroll
      for (int d = 0; d < 8; ++d) acc_row(cp + d * 16, ((d >> 1) & 3) << 2);
    }
    acc_row(sC + 48 * 16, 0);   // j=48: xw(48)=0
    acc_row(sC + 49 * 16, 0);   // j=49: xw(49)=0
    *(float2*)(sY + lane * 6)     = make_float2(ya2[0].x, ya2[0].y);
    *(float2*)(sY + lane * 6 + 2) = make_float2(ya2[1].x, ya2[1].y);
    *(float2*)(sY + lane * 6 + 4) = make_float2(ya2[2].x, ya2[2].y);
  }
  WAVE_FENCE();      // sY -> phase 7 (cross-lane)

  // ---- Phase 7: x_gru — 48 lanes (8 per h) + shfl reduce ----
  if (lane < 48) {
    const int h = lane >> 3;
    const int m = lane & 7;
    float s = 0.0f;
    #pragma unroll
    for (int k = 0; k < 7; ++k) {
      const int idx = m + (k << 3);
      if (idx < LSEQ) s += sY[h * LSEQ + idx];
    }
    s += __shfl_xor(s, 1);
    s += __shfl_xor(s, 2);
    s += __shfl_xor(s, 4);
    if (m == 0) sFE[48 + h] = s;
  }
  WAVE_FENCE();      // sFE complete -> phase 8

  // ---- Phase 8: fc — 64 lanes (32 per output) + shfl reduce ----
  {
    const int oo = lane & 1;
    const int kk = lane >> 1;
    float s = fc3w[oo * 54 + kk] * sFE[kk];
    if (kk < 22) s = fmaf(fc3w[oo * 54 + kk + 32], sFE[kk + 32], s);
    s += __shfl_xor(s, 2);
    s += __shfl_xor(s, 4);
    s += __shfl_xor(s, 8);
    s += __shfl_xor(s, 16);
    s += __shfl_xor(s, 32);
    if (lane < 2) out[(size_t)b * 2 + lane] = s + fc3b[lane];
  }
}

extern "C" void kernel_launch(void* const* d_in, const int* in_sizes, int n_in,
                              void* d_out, int out_size, void* d_ws, size_t ws_size,
                              hipStream_t stream) {
  (void)in_sizes; (void)n_in; (void)d_ws; (void)ws_size; (void)out_size;
  fused_kernel<<<BATCH, 64, 0, stream>>>(
      (const float*)d_in[0],
      (const float*)d_in[1],  (const float*)d_in[2],
      (const float*)d_in[3],  (const float*)d_in[4],
      (const float*)d_in[5],  (const float*)d_in[6],
      (const float*)d_in[7],  (const float*)d_in[8],
      (const float*)d_in[9],  (const float*)d_in[10],
      (const float*)d_in[11], (const float*)d_in[12],
      (const float*)d_in[13], (const float*)d_in[14],
      (const float*)d_in[15], (const float*)d_in[16],
      (float*)d_out);
}